// Round 6
// baseline (273.484 us; speedup 1.0000x reference)
//
#include <hip/hip_runtime.h>
#include <math.h>

#define B_N 2048
#define KK 128
#define MM 640
#define HS 136    // k-stride (elems) for bf16 panels (mult of 8 for b128 align, breaks pow2 banks)
#define ZSS 40    // Z row stride (bf16)
#define SXS 12    // SX row stride (fp32)
#define ALPHA (1.0f/128.0f)
#define VARTHETA 0.1f
#define PMAXV 10.0f
#define BIGV 1000000000.0f

typedef __attribute__((ext_vector_type(8))) short short8;
typedef __attribute__((ext_vector_type(4))) short short4v;
typedef __attribute__((ext_vector_type(4))) float floatx4;
typedef __attribute__((ext_vector_type(4))) __bf16 bf16x4;

static __device__ __forceinline__ unsigned short f2bf(float f) {
    return __builtin_bit_cast(unsigned short, (__bf16)f);   // RNE, v_cvt on gfx950
}
static __device__ __forceinline__ short4v cvt4(floatx4 v) {
    return __builtin_bit_cast(short4v, __builtin_convertvector(v, bf16x4));
}
static __device__ __forceinline__ float bf2f(unsigned short h) {
    unsigned u = ((unsigned)h) << 16;
    return __builtin_bit_cast(float, u);
}
static __device__ __forceinline__ short8 pack8(floatx4 lo, floatx4 hi) {
    short4v a = cvt4(lo), b4 = cvt4(hi);
    return __builtin_shufflevector(a, b4, 0, 1, 2, 3, 4, 5, 6, 7);
}
// Launder a uniform pointer through an SGPR no-op so the ph10 reload can't be CSE'd
// with the ph2 A-extraction (which would extend A's live range -> R6/R7-style spill).
static __device__ __forceinline__ const float* launder_ptr(const float* p) {
    unsigned long long v = (unsigned long long)p;
    asm volatile("" : "+s"(v));
    return (const float*)v;
}

// R10 = R9 overlay structure, launch bounds (512,4).
// R9's (512,6) invited the allocator down to VGPR=40 — too few to keep the staging
// loop's 8 float4 loads in flight (32 VGPRs of load data) -> serialized HBM latency
// on every block's critical path (95us vs R0's 79.6 despite 56% occupancy).
// (512,4) caps VGPR at 128; natural allocation for this code is ~64 (R0 evidence),
// which keeps staging pipelined AND stays <=85 so LDS (51200 -> 3 blocks/CU) remains
// the binding occupancy limit (24 waves/CU vs R0's 16).
//  Overlay H (34816 B): hwb staging->ph2; then w1aT@0 (staged in ph3), c2T@8704,
//  zbp@17408, eT@27648, t0f@29696; cw@0 in ph10 (global-reload butterfly).
#define H_W1AT 0
#define H_C2T  8704
#define H_ZBP  17408
#define H_ET   27648
#define H_T0F  29696

__global__ __launch_bounds__(512, 4)
void unfold_pocs_kernel(
    const int* __restrict__ num_itr_p, const int* __restrict__ kth_p,
    const float* __restrict__ HW, const float* __restrict__ x0,
    const float* __restrict__ nu3_p, const float* __restrict__ tg_p,
    const float* __restrict__ g1_W0a, const float* __restrict__ g1_W1a,
    const float* __restrict__ g1_W0b, const float* __restrict__ g1_W1b,
    const float* __restrict__ g2_W0a, const float* __restrict__ g2_W1a,
    const float* __restrict__ g2_W0b, const float* __restrict__ g2_W1b,
    float* __restrict__ out)
{
    __shared__ __align__(16) unsigned char H[KK*HS*2];      // 34816 B overlay pool
    __shared__ __align__(16) float SXs_s[KK*SXS];           // 6144 B (ph1->ph2)
    __shared__ __align__(16) float xb[MM];                  // 2560 B
    __shared__ __align__(16) unsigned short xbf[5*HS];      // 1360 B, X1 bf16 [f][k]
    __shared__ __align__(16) unsigned short x2bf[KK*8];     // 2048 B, X2 bf16 [m][f pad]
    __shared__ __align__(16) unsigned short w1abf[32*8];    // 512 B, W1a_bot [n][k pad]
    __shared__ __align__(16) unsigned short w0abf[32*8];    // 512 B, W0a_bot [n][k pad]
    __shared__ __align__(16) float g1w0a[160], g1w1a[160];
    __shared__ __align__(16) float g1w0b[64],  g1w1b[64];
    __shared__ __align__(16) float w0b2[160],  w1b2[160];   // 32x5 f32
    __shared__ float red[16];

    unsigned short* hwb  = (unsigned short*)H;              // staging -> ph2
    unsigned short* w1aT = (unsigned short*)(H + H_W1AT);   // ph3 -> ph4
    unsigned short* c2T  = (unsigned short*)(H + H_C2T);    // ph4 -> ph5
    unsigned short* zbp  = (unsigned short*)(H + H_ZBP);    // ph5 -> ph6
    unsigned short* eT   = (unsigned short*)(H + H_ET);     // ph6 -> ph7
    float*          t0f  = (float*)(H + H_T0F);             // ph6 -> ph7
    float*          cw   = (float*)H;                       // ph10 partials
    float*          SXs  = SXs_s;

    const int t = threadIdx.x;
    const int b = blockIdx.x;
    const float* HWb = HW + (size_t)b * (KK*KK);

    const int wv = t >> 6, lane = t & 63, quad = lane >> 4, lr = lane & 15;
    const int arow = wv*16 + lr;

    // ---------- staging (R0 pattern: coalesced HW -> bf16 LDS; NO w1aT here) ----------
    #pragma unroll
    for (int it = 0; it < 8; ++it) {            // hw -> bf16 LDS
        int qi = it * 512 + t;                  // 4096 float4-quads
        int rrow = qi >> 5, q = qi & 31;
        floatx4 v = *(const floatx4*)(HWb + rrow*KK + q*4);
        *(short4v*)&hwb[rrow*HS + q*4] = cvt4(v);
    }
    {   // W1a_bot / W0a_bot (5x32) -> [n][k0..7], zero-padded
        const int n = (t & 255) >> 3, j = t & 7;
        if (t < 256) w1abf[t]       = (j < 5) ? f2bf(g2_W1a[(KK + j)*32 + n]) : (unsigned short)0;
        else if (t < 512) w0abf[t - 256] = (j < 5) ? f2bf(g2_W0a[(KK + j)*32 + n]) : (unsigned short)0;
    }
    if (t < 160) {
        floatx4 v = *(const floatx4*)(x0 + (size_t)b*MM + t*4);
        *(floatx4*)(xb + t*4) = v;
        *(short4v*)&xbf[(t >> 5)*HS + ((t*4) & 127)] = cvt4(v);   // X1 bf16 copy
        g1w0a[t] = g1_W0a[t];
        g1w1a[t] = g1_W1a[t];
        w0b2[t]  = g2_W0b[t];
        w1b2[t]  = g2_W1b[t];
    }
    if (t < 64) { g1w0b[t] = g1_W0b[t]; g1w1b[t] = g1_W1b[t]; }
    __syncthreads();

    // ---------- phase 1: SX = HW@X1 (MFMA, A and B from LDS) ----------
    {
        floatx4 acc = {0.f, 0.f, 0.f, 0.f};
        const int ns = lr < 5 ? lr : 4;
        #pragma unroll
        for (int kt = 0; kt < 4; ++kt) {
            short8 a  = *(const short8*)&hwb[arow*HS + kt*32 + quad*8];
            short8 bb = *(const short8*)&xbf[ns*HS   + kt*32 + quad*8];
            acc = __builtin_amdgcn_mfma_f32_16x16x32_bf16(a, bb, acc, 0, 0, 0);
        }
        if (lr < 5) {
            #pragma unroll
            for (int r = 0; r < 4; ++r)
                SXs[(wv*16 + quad*4 + r)*SXS + lr] = acc[r];
        }
    }
    __syncthreads();

    const int row = t >> 2, g = t & 3;          // 4 lanes per row for row-ops

    // ---------- phase 2: g1 -> per-wave partials (last hwb reads) ----------
    short8 A[4];                                // live ph2-end -> ph7 only
    {
        float sx[5], x1r[5];
        #pragma unroll
        for (int f = 0; f < 5; ++f) { sx[f] = SXs[row*SXS + f]; x1r[f] = xb[f*KK + row]; }

        float zb0p0=0, zb0p1=0, zb1p0=0, zb1p1=0;
        #pragma unroll
        for (int hh = 0; hh < 8; ++hh) {
            int h = 8*g + hh;
            float a = 0.0f;
            #pragma unroll
            for (int f = 0; f < 5; ++f) a += x1r[f]*g1w0a[f*32+h] + sx[f]*g1w1a[f*32+h];
            a = fmaxf(a, 0.0f);
            zb0p0 += a * g1w0b[h*2+0];
            zb0p1 += a * g1w0b[h*2+1];
            zb1p0 += a * g1w1b[h*2+0];
            zb1p1 += a * g1w1b[h*2+1];
        }
        float mp = 0.0f;                        // colsum of hw column 'row' (LDS walk)
        for (int w = 0; w < 32; ++w) {
            int i = 4*w + g;
            mp += bf2f(hwb[i*HS + row]);
        }
        mp += __shfl_xor(mp, 1); mp += __shfl_xor(mp, 2);
        float m = mp * (1.0f/KK);
        float c0 = zb0p0*(1.0f/KK) + m*zb1p0;
        float c1 = zb0p1*(1.0f/KK) + m*zb1p1;
        #pragma unroll
        for (int s = 1; s < 64; s <<= 1) { c0 += __shfl_xor(c0, s); c1 += __shfl_xor(c1, s); }
        if (lane == 0) { red[wv*2] = c0; red[wv*2 + 1] = c1; }
    }
    // extract A-fragments from hwb (final hwb use; H is repurposed after the barrier)
    #pragma unroll
    for (int kt = 0; kt < 4; ++kt)
        A[kt] = *(const short8*)&hwb[arow*HS + kt*32 + quad*8];
    __syncthreads();

    // ---------- phase 3: lbd + x update + x2bf build + DEFERRED w1aT staging ----------
    {
        float lbd0 = 0.f, lbd1 = 0.f;
        #pragma unroll
        for (int w2 = 0; w2 < 8; ++w2) { lbd0 += red[w2*2]; lbd1 += red[w2*2+1]; }
        lbd0 = fmaxf(lbd0, 0.0f); lbd1 = fmaxf(lbd1, 0.0f);

        const int i0 = 2*t, m = i0 >> 3, f0 = i0 & 7;     // f0 in {0,2,4,6}
        float va = (f0     < 5) ? xb[f0*KK + m]     : 0.f;
        float vb = (f0 + 1 < 5) ? xb[(f0+1)*KK + m] : 0.f;
        if (f0 == 0) { vb = vb - lbd0 * (ALPHA / (1.0f + vb)); xb[KK + m]   = vb; }
        if (f0 == 4) { va = va + lbd1 * (ALPHA * VARTHETA);    xb[4*KK + m] = va; }
        ushort2 p; p.x = f2bf(va); p.y = f2bf(vb);
        *(ushort2*)&x2bf[i0] = p;
    }
    {   // W1a_top (128x32) -> transposed bf16 [n][k] into H@0 (hwb rows 0..16 now dead)
        const int n = t & 31, seg = t >> 5;     // 16 segs of 8 k
        unsigned short tmp[8];
        #pragma unroll
        for (int i = 0; i < 8; ++i) tmp[i] = f2bf(g2_W1a[(seg*8 + i)*32 + n]);
        *(short8*)&w1aT[n*HS + seg*8] = *(short8*)tmp;
    }
    __syncthreads();

    // ---------- phase 4: MFMA1: C2 = W0a_top + X2@W1a_bot + HW@W1a_top -> c2T ----------
    #pragma unroll
    for (int nt = 0; nt < 2; ++nt) {
        const int n = nt*16 + lr, mmb = wv*16 + quad*4;
        floatx4 acc = {0.f, 0.f, 0.f, 0.f};
        short8 ax2 = {0,0,0,0,0,0,0,0}, bx2 = {0,0,0,0,0,0,0,0};
        if (quad == 0) {
            ax2 = *(const short8*)&x2bf[(wv*16 + lr)*8];
            bx2 = *(const short8*)&w1abf[n*8];
        }
        acc = __builtin_amdgcn_mfma_f32_16x16x32_bf16(ax2, bx2, acc, 0, 0, 0);
        #pragma unroll
        for (int kt = 0; kt < 4; ++kt) {
            short8 bb = *(const short8*)&w1aT[n*HS + kt*32 + quad*8];
            acc = __builtin_amdgcn_mfma_f32_16x16x32_bf16(A[kt], bb, acc, 0, 0, 0);
        }
        ushort4 pe;
        pe.x = f2bf(acc[0] + g2_W0a[(mmb+0)*32 + n]);
        pe.y = f2bf(acc[1] + g2_W0a[(mmb+1)*32 + n]);
        pe.z = f2bf(acc[2] + g2_W0a[(mmb+2)*32 + n]);
        pe.w = f2bf(acc[3] + g2_W0a[(mmb+3)*32 + n]);
        *(ushort4*)&c2T[n*HS + mmb] = pe;
    }
    __syncthreads();

    // ---------- phase 5: MFMA2: Z = relu(HW@C2 + X2@W0a_bot) -> zbp ----------
    #pragma unroll
    for (int nt = 0; nt < 2; ++nt) {
        const int n = nt*16 + lr, mmb = wv*16 + quad*4;
        floatx4 acc = {0.f, 0.f, 0.f, 0.f};
        short8 ax2 = {0,0,0,0,0,0,0,0}, bx2 = {0,0,0,0,0,0,0,0};
        if (quad == 0) {
            ax2 = *(const short8*)&x2bf[(wv*16 + lr)*8];
            bx2 = *(const short8*)&w0abf[n*8];
        }
        acc = __builtin_amdgcn_mfma_f32_16x16x32_bf16(ax2, bx2, acc, 0, 0, 0);
        #pragma unroll
        for (int kt = 0; kt < 4; ++kt) {
            short8 bb = *(const short8*)&c2T[n*HS + kt*32 + quad*8];
            acc = __builtin_amdgcn_mfma_f32_16x16x32_bf16(A[kt], bb, acc, 0, 0, 0);
        }
        #pragma unroll
        for (int r = 0; r < 4; ++r)
            zbp[(mmb + r)*ZSS + n] = f2bf(fmaxf(acc[r], 0.0f));
    }
    __syncthreads();

    // ---------- phase 6: E = Z@W1b2 -> eT, t0 = Z@W0b2 -> t0f ----------
    {
        float ev[5] = {0,0,0,0,0}, t0v[5] = {0,0,0,0,0};
        short8 zrow = *(const short8*)&zbp[row*ZSS + g*8];
        #pragma unroll
        for (int hh = 0; hh < 8; ++hh) {
            int h = 8*g + hh;
            float zv = bf2f((unsigned short)zrow[hh]);
            #pragma unroll
            for (int c = 0; c < 5; ++c) {
                ev[c]  += zv * w1b2[h*5 + c];
                t0v[c] += zv * w0b2[h*5 + c];
            }
        }
        #pragma unroll
        for (int c = 0; c < 5; ++c) {
            ev[c]  += __shfl_xor(ev[c], 1);  ev[c]  += __shfl_xor(ev[c], 2);
            t0v[c] += __shfl_xor(t0v[c], 1); t0v[c] += __shfl_xor(t0v[c], 2);
        }
        if (g == 0) {
            #pragma unroll
            for (int c = 0; c < 5; ++c) {
                eT[c*HS + row]  = f2bf(ev[c]);
                t0f[row*8 + c]  = t0v[c];
            }
        }
    }
    __syncthreads();

    // ---------- phase 7: tilde = t0 + HW@E ; x += tilde^T (last use of A) ----------
    {
        floatx4 acc = {0.f, 0.f, 0.f, 0.f};
        const int ns = lr < 5 ? lr : 4;
        #pragma unroll
        for (int kt = 0; kt < 4; ++kt) {
            short8 bb = *(const short8*)&eT[ns*HS + kt*32 + quad*8];
            acc = __builtin_amdgcn_mfma_f32_16x16x32_bf16(A[kt], bb, acc, 0, 0, 0);
        }
        if (lr < 5) {
            #pragma unroll
            for (int r = 0; r < 4; ++r) {
                int mm = wv*16 + quad*4 + r;
                xb[lr*KK + mm] += acc[r] + t0f[mm*8 + lr];
            }
        }
    }
    __syncthreads();

    // ---------- phase 8: f = sum(x[:K]) - PMAX (redundant per-thread) ----------
    float pv = (t < KK) ? xb[t] : 0.0f;
    #pragma unroll
    for (int s = 1; s < 64; s <<= 1) pv += __shfl_xor(pv, s);
    if (lane == 0) red[wv] = pv;
    __syncthreads();
    float fv = -PMAXV;
    #pragma unroll
    for (int w2 = 0; w2 < 8; ++w2) fv += red[w2];

    const int num_itr = num_itr_p[0], kth = kth_p[0];
    const bool flag = (kth == num_itr - 1);
    const float nu3 = nu3_p[0], tg = tg_p[0];
    const float onu = 1.0f + nu3, otg = 1.0f + tg;
    const float Vnu = 1.0f - 1.0f/(onu*onu), Vg = 1.0f - 1.0f/(otg*otg);
    float* outx = out + (size_t)b * MM;

    // ---------- phase 9: clamp + store ----------
    #pragma unroll
    for (int r2 = 0; r2 < 2; ++r2) {
        int idx = r2*512 + t;
        if (idx < MM) {
            float v = xb[idx];
            if (idx < KK && fv > 0.0f) v -= fv * (1.0f/KK);
            v = fmaxf(v, (idx >= KK   && idx < 2*KK) ? nu3 : 0.0f);
            v = fminf(v, (idx >= 2*KK && idx < 3*KK) ? tg  : BIGV);
            v = fmaxf(v, (idx >= 3*KK && idx < 4*KK) ? Vnu : 0.0f);
            v = fminf(v, (idx >= 3*KK && idx < 4*KK) ? Vg  : BIGV);
            if (flag) v = fmaxf(v, 0.0f);
            xb[idx] = v;
            outx[idx] = v;
        }
    }

    // ---------- phase 10: extra outputs (flag; global-reload butterfly, cw in H) ----------
    if (flag) {
        __syncthreads();
        const size_t O1 = (size_t)B_N*MM;
        const size_t OK = (size_t)B_N*KK;
        if (t < KK) {
            float xg = xb[2*KK + t], xv = xb[3*KK + t];
            float u1 = 1.0f + xg;
            out[O1 + (size_t)b*KK + t]      = 1.0f - 1.0f/(u1*u1) - xv;   // f5
            out[O1 + OK + (size_t)b*KK + t] = sqrtf(xv) - xb[4*KK + t];   // f6
        }
        {   // dp[j] = sum_i p[i]*hw_bf16[i][j] via butterfly over reloaded fragments
            const float* hwr = launder_ptr(HWb);
            float pval = xb[arow];
            #pragma unroll
            for (int kt = 0; kt < 4; ++kt) {
                const float* arp = hwr + arow*KK + kt*32 + quad*8;
                floatx4 lo = *(const floatx4*)(arp);
                floatx4 hi = *(const floatx4*)(arp + 4);
                short8 ad = pack8(lo, hi);
                float v[8];
                #pragma unroll
                for (int j = 0; j < 8; ++j) v[j] = pval * bf2f((unsigned short)ad[j]);
                #pragma unroll
                for (int s = 1; s < 16; s <<= 1) {
                    #pragma unroll
                    for (int j = 0; j < 8; ++j) v[j] += __shfl_xor(v[j], s);
                }
                if (lr == 0) {
                    #pragma unroll
                    for (int j = 0; j < 8; ++j) cw[wv*KK + kt*32 + quad*8 + j] = v[j];
                }
            }
        }
        __syncthreads();
        if (t < KK) {
            float dp = 0.0f;
            #pragma unroll
            for (int w = 0; w < 8; ++w) dp += cw[w*KK + t];
            float p_  = xb[t], nuv = xb[KK + t], xg = xb[2*KK + t];
            float diag = bf2f(f2bf(HWb[t*KK + t]));   // match bf16 rounding of dp terms
            float top  = p_ * diag;
            float down = dp - top + 1.0f;
            out[O1 + 2*OK + (size_t)b*KK + t] = top - down * xg;          // f4
            out[O1 + 3*OK + (size_t)b*KK + t] = nuv * down - top;         // f2
        }
    }
}

extern "C" void kernel_launch(void* const* d_in, const int* in_sizes, int n_in,
                              void* d_out, int out_size, void* d_ws, size_t ws_size,
                              hipStream_t stream) {
    unfold_pocs_kernel<<<dim3(B_N), dim3(512), 0, stream>>>(
        (const int*)d_in[0], (const int*)d_in[1],
        (const float*)d_in[2], (const float*)d_in[3],
        (const float*)d_in[4], (const float*)d_in[5],
        (const float*)d_in[12], (const float*)d_in[13],
        (const float*)d_in[14], (const float*)d_in[15],
        (const float*)d_in[16], (const float*)d_in[17],
        (const float*)d_in[18], (const float*)d_in[19],
        (float*)d_out);
}

// Round 7
// 255.284 us; speedup vs baseline: 1.0713x; 1.0713x over previous
//
#include <hip/hip_runtime.h>
#include <math.h>

#define B_N 2048
#define KK 128
#define MM 640
#define HS 136    // k-stride (elems) for bf16 panels (mult of 8 for b128 align, breaks pow2 banks)
#define ZSS 40    // Z row stride (bf16)
#define SXS 12    // SX row stride (fp32)
#define ALPHA (1.0f/128.0f)
#define VARTHETA 0.1f
#define PMAXV 10.0f
#define BIGV 1000000000.0f

typedef __attribute__((ext_vector_type(8))) short short8;
typedef __attribute__((ext_vector_type(4))) short short4v;
typedef __attribute__((ext_vector_type(4))) float floatx4;
typedef __attribute__((ext_vector_type(4))) __bf16 bf16x4;

static __device__ __forceinline__ unsigned short f2bf(float f) {
    return __builtin_bit_cast(unsigned short, (__bf16)f);   // RNE, v_cvt on gfx950
}
static __device__ __forceinline__ short4v cvt4(floatx4 v) {
    return __builtin_bit_cast(short4v, __builtin_convertvector(v, bf16x4));
}
static __device__ __forceinline__ float bf2f(unsigned short h) {
    unsigned u = ((unsigned)h) << 16;
    return __builtin_bit_cast(float, u);
}
static __device__ __forceinline__ short8 pack8(floatx4 lo, floatx4 hi) {
    short4v a = cvt4(lo), b4 = cvt4(hi);
    return __builtin_shufflevector(a, b4, 0, 1, 2, 3, 4, 5, 6, 7);
}

// LDS pool overlays (time-sliced), R0 layout:
//  poolA (10240 B): w1aT (32x136 bf16, staging->MFMA1)  then  zbp (128x40 bf16, MFMA2->E)
//  poolB (8704 B) : SXs (128x12 f32, ph1->ph2) -> c2T (32x136 bf16, MFMA1->MFMA2)
//                   -> eT (5x136 bf16 @0) + t0f (128x8 f32 @2048)  (ph6->ph7)
#define POOLA_OFF 0
#define POOLB_OFF 10240
#define POOL_BYTES (10240 + 8704)

// R11 = R0 (79.6us proven) with the pre-ph1 global staging JOIN removed.
// Insight from R5-R10: this kernel is per-block-critical-path bound, not occupancy
// bound (every higher-occupancy overlay variant had longer block latency and lost).
// ph1 is wave-local: wave wv's MFMA reads only hwb rows [wv*16,wv*16+16), and its B
// operand (X1, 2.5KB) can come from global with the identical f32->bf16 RNE path.
// So each wave: stages ITS OWN 16 HW rows (8 float4/lane into named regs,
// sched_barrier(0) pins all loads issued before converts -> forced 8-deep pipeline),
// ds_writes, then MFMAs immediately -- no block barrier between staging and ph1.
// First __syncthreads moves AFTER ph1 (covers hwb for ph2 colsum + xb/weights/w1aT).
// xbf deleted (only ph1 used it). ph2..ph10 byte-for-byte R0. LDS ~62.5KB, 2 blk/CU.
__global__ __launch_bounds__(512, 4)
void unfold_pocs_kernel(
    const int* __restrict__ num_itr_p, const int* __restrict__ kth_p,
    const float* __restrict__ HW, const float* __restrict__ x0,
    const float* __restrict__ nu3_p, const float* __restrict__ tg_p,
    const float* __restrict__ g1_W0a, const float* __restrict__ g1_W1a,
    const float* __restrict__ g1_W0b, const float* __restrict__ g1_W1b,
    const float* __restrict__ g2_W0a, const float* __restrict__ g2_W1a,
    const float* __restrict__ g2_W0b, const float* __restrict__ g2_W1b,
    float* __restrict__ out)
{
    __shared__ __align__(16) unsigned short hwb[KK*HS];     // 34816 B, bf16 hw row-major
    __shared__ __align__(16) unsigned char pool[POOL_BYTES];
    __shared__ __align__(16) float xb[MM];                  // 2560 B
    __shared__ __align__(16) unsigned short x2bf[KK*8];     // 2048 B, X2 bf16 [m][f(0..7 pad)]
    __shared__ __align__(16) unsigned short w1abf[32*8];    // 512 B, W1a_bot [n][k pad]
    __shared__ __align__(16) unsigned short w0abf[32*8];    // 512 B, W0a_bot [n][k pad]
    __shared__ __align__(16) float g1w0a[160], g1w1a[160];
    __shared__ __align__(16) float g1w0b[64],  g1w1b[64];
    __shared__ __align__(16) float w0b2[160],  w1b2[160];   // 32x5 f32
    __shared__ float red[16];

    unsigned short* w1aT = (unsigned short*)(pool + POOLA_OFF);
    unsigned short* zbp  = (unsigned short*)(pool + POOLA_OFF);
    float*          SXs  = (float*)(pool + POOLB_OFF);
    unsigned short* c2T  = (unsigned short*)(pool + POOLB_OFF);
    unsigned short* eT   = (unsigned short*)(pool + POOLB_OFF);
    float*          t0f  = (float*)(pool + POOLB_OFF + 2048);

    const int t = threadIdx.x;
    const int b = blockIdx.x;
    const float* HWb = HW + (size_t)b * (KK*KK);

    const int wv = t >> 6, lane = t & 63, quad = lane >> 4, lr = lane & 15;
    const int arow = wv*16 + lr;

    // ---------- region 0: per-wave HW-row staging + B-frag loads (no join) ----------
    floatx4 hv[8];
    #pragma unroll
    for (int it = 0; it < 8; ++it) {            // own wave's 16 rows: 512 quads/wave
        int qi = it*64 + lane;
        int r = qi >> 5, q = qi & 31;
        hv[it] = *(const floatx4*)(HWb + (wv*16 + r)*KK + q*4);
    }
    const int ns = lr < 5 ? lr : 4;
    floatx4 bv[8];                              // ph1 B-frags straight from x0
    #pragma unroll
    for (int kt = 0; kt < 4; ++kt) {
        const float* xp = x0 + (size_t)b*MM + ns*KK + kt*32 + quad*8;
        bv[2*kt]   = *(const floatx4*)(xp);
        bv[2*kt+1] = *(const floatx4*)(xp + 4);
    }
    __builtin_amdgcn_sched_barrier(0);          // pin: all 16 loads issued before converts

    #pragma unroll
    for (int it = 0; it < 8; ++it) {
        int qi = it*64 + lane;
        int r = qi >> 5, q = qi & 31;
        *(short4v*)&hwb[(wv*16 + r)*HS + q*4] = cvt4(hv[it]);
    }
    {   // W1a_top (128x32) -> transposed bf16 [n][k] (first use: ph4)
        const int n = t & 31, seg = t >> 5;     // 16 segs of 8 k
        unsigned short tmp[8];
        #pragma unroll
        for (int i = 0; i < 8; ++i) tmp[i] = f2bf(g2_W1a[(seg*8 + i)*32 + n]);
        *(short8*)&w1aT[n*HS + seg*8] = *(short8*)tmp;
    }
    {   // W1a_bot / W0a_bot (5x32) -> [n][k0..7], zero-padded
        const int n = (t & 255) >> 3, j = t & 7;
        if (t < 256) w1abf[t]       = (j < 5) ? f2bf(g2_W1a[(KK + j)*32 + n]) : (unsigned short)0;
        else if (t < 512) w0abf[t - 256] = (j < 5) ? f2bf(g2_W0a[(KK + j)*32 + n]) : (unsigned short)0;
    }
    if (t < 160) {
        floatx4 v = *(const floatx4*)(x0 + (size_t)b*MM + t*4);
        *(floatx4*)(xb + t*4) = v;
        g1w0a[t] = g1_W0a[t];
        g1w1a[t] = g1_W1a[t];
        w0b2[t]  = g2_W0b[t];
        w1b2[t]  = g2_W1b[t];
    }
    if (t < 64) { g1w0b[t] = g1_W0b[t]; g1w1b[t] = g1_W1b[t]; }
    __builtin_amdgcn_sched_barrier(0);          // keep A1 ds_reads below the hwb writes

    // ---------- phase 1 (wave-local, no block barrier before): SX = HW@X1 ----------
    {
        short8 A1[4];                           // own rows, just staged by this wave
        #pragma unroll
        for (int kt = 0; kt < 4; ++kt)
            A1[kt] = *(const short8*)&hwb[arow*HS + kt*32 + quad*8];
        floatx4 acc = {0.f, 0.f, 0.f, 0.f};
        #pragma unroll
        for (int kt = 0; kt < 4; ++kt) {
            short8 bb = pack8(bv[2*kt], bv[2*kt+1]);   // same RNE bf16 as old xbf path
            acc = __builtin_amdgcn_mfma_f32_16x16x32_bf16(A1[kt], bb, acc, 0, 0, 0);
        }
        if (lr < 5) {
            #pragma unroll
            for (int r = 0; r < 4; ++r)
                SXs[(wv*16 + quad*4 + r)*SXS + lr] = acc[r];
        }
    }
    __syncthreads();    // barrier #1: hwb (all waves), SXs, xb, weights, w1aT all visible

    const int row = t >> 2, g = t & 3;          // 4 lanes per row for row-ops

    // ---------- phase 2: g1 -> per-wave partials ----------
    {
        float sx[5], x1r[5];
        #pragma unroll
        for (int f = 0; f < 5; ++f) { sx[f] = SXs[row*SXS + f]; x1r[f] = xb[f*KK + row]; }

        float zb0p0=0, zb0p1=0, zb1p0=0, zb1p1=0;
        #pragma unroll
        for (int hh = 0; hh < 8; ++hh) {
            int h = 8*g + hh;
            float a = 0.0f;
            #pragma unroll
            for (int f = 0; f < 5; ++f) a += x1r[f]*g1w0a[f*32+h] + sx[f]*g1w1a[f*32+h];
            a = fmaxf(a, 0.0f);
            zb0p0 += a * g1w0b[h*2+0];
            zb0p1 += a * g1w0b[h*2+1];
            zb1p0 += a * g1w1b[h*2+0];
            zb1p1 += a * g1w1b[h*2+1];
        }
        float mp = 0.0f;                        // colsum of hw column 'row'
        for (int w = 0; w < 32; ++w) {
            int i = 4*w + g;
            mp += bf2f(hwb[i*HS + row]);
        }
        mp += __shfl_xor(mp, 1); mp += __shfl_xor(mp, 2);
        float m = mp * (1.0f/KK);
        float c0 = zb0p0*(1.0f/KK) + m*zb1p0;
        float c1 = zb0p1*(1.0f/KK) + m*zb1p1;
        #pragma unroll
        for (int s = 1; s < 64; s <<= 1) { c0 += __shfl_xor(c0, s); c1 += __shfl_xor(c1, s); }
        if (lane == 0) { red[wv*2] = c0; red[wv*2 + 1] = c1; }
    }
    __syncthreads();

    // ---------- phase 3: lbd (redundant) + x update + x2bf build (race-free) ----------
    {
        float lbd0 = 0.f, lbd1 = 0.f;
        #pragma unroll
        for (int w2 = 0; w2 < 8; ++w2) { lbd0 += red[w2*2]; lbd1 += red[w2*2+1]; }
        lbd0 = fmaxf(lbd0, 0.0f); lbd1 = fmaxf(lbd1, 0.0f);

        const int i0 = 2*t, m = i0 >> 3, f0 = i0 & 7;     // f0 in {0,2,4,6}
        float va = (f0     < 5) ? xb[f0*KK + m]     : 0.f;
        float vb = (f0 + 1 < 5) ? xb[(f0+1)*KK + m] : 0.f;
        if (f0 == 0) { vb = vb - lbd0 * (ALPHA / (1.0f + vb)); xb[KK + m]   = vb; }
        if (f0 == 4) { va = va + lbd1 * (ALPHA * VARTHETA);    xb[4*KK + m] = va; }
        ushort2 p; p.x = f2bf(va); p.y = f2bf(vb);
        *(ushort2*)&x2bf[i0] = p;
    }
    __syncthreads();

    // ---------- A-fragments from LDS (live ph4-ph7 only; R0-proven pressure) ----------
    short8 A[4];
    #pragma unroll
    for (int kt = 0; kt < 4; ++kt)
        A[kt] = *(const short8*)&hwb[arow*HS + kt*32 + quad*8];

    // ---------- phase 4: MFMA1: C2 = W0a_top + X2@W1a_bot + HW@W1a_top -> c2T ----------
    #pragma unroll
    for (int nt = 0; nt < 2; ++nt) {
        const int n = nt*16 + lr, mmb = wv*16 + quad*4;
        floatx4 acc = {0.f, 0.f, 0.f, 0.f};
        short8 ax2 = {0,0,0,0,0,0,0,0}, bx2 = {0,0,0,0,0,0,0,0};
        if (quad == 0) {
            ax2 = *(const short8*)&x2bf[(wv*16 + lr)*8];
            bx2 = *(const short8*)&w1abf[n*8];
        }
        acc = __builtin_amdgcn_mfma_f32_16x16x32_bf16(ax2, bx2, acc, 0, 0, 0);
        #pragma unroll
        for (int kt = 0; kt < 4; ++kt) {
            short8 bb = *(const short8*)&w1aT[n*HS + kt*32 + quad*8];
            acc = __builtin_amdgcn_mfma_f32_16x16x32_bf16(A[kt], bb, acc, 0, 0, 0);
        }
        ushort4 pe;
        pe.x = f2bf(acc[0] + g2_W0a[(mmb+0)*32 + n]);
        pe.y = f2bf(acc[1] + g2_W0a[(mmb+1)*32 + n]);
        pe.z = f2bf(acc[2] + g2_W0a[(mmb+2)*32 + n]);
        pe.w = f2bf(acc[3] + g2_W0a[(mmb+3)*32 + n]);
        *(ushort4*)&c2T[n*HS + mmb] = pe;
    }
    __syncthreads();

    // ---------- phase 5: MFMA2: Z = relu(HW@C2 + X2@W0a_bot) -> zbp ----------
    #pragma unroll
    for (int nt = 0; nt < 2; ++nt) {
        const int n = nt*16 + lr, mmb = wv*16 + quad*4;
        floatx4 acc = {0.f, 0.f, 0.f, 0.f};
        short8 ax2 = {0,0,0,0,0,0,0,0}, bx2 = {0,0,0,0,0,0,0,0};
        if (quad == 0) {
            ax2 = *(const short8*)&x2bf[(wv*16 + lr)*8];
            bx2 = *(const short8*)&w0abf[n*8];
        }
        acc = __builtin_amdgcn_mfma_f32_16x16x32_bf16(ax2, bx2, acc, 0, 0, 0);
        #pragma unroll
        for (int kt = 0; kt < 4; ++kt) {
            short8 bb = *(const short8*)&c2T[n*HS + kt*32 + quad*8];
            acc = __builtin_amdgcn_mfma_f32_16x16x32_bf16(A[kt], bb, acc, 0, 0, 0);
        }
        #pragma unroll
        for (int r = 0; r < 4; ++r)
            zbp[(mmb + r)*ZSS + n] = f2bf(fmaxf(acc[r], 0.0f));
    }
    __syncthreads();

    // ---------- phase 6: E = Z@W1b2 -> eT, t0 = Z@W0b2 -> t0f ----------
    {
        float ev[5] = {0,0,0,0,0}, t0v[5] = {0,0,0,0,0};
        short8 zrow = *(const short8*)&zbp[row*ZSS + g*8];
        #pragma unroll
        for (int hh = 0; hh < 8; ++hh) {
            int h = 8*g + hh;
            float zv = bf2f((unsigned short)zrow[hh]);
            #pragma unroll
            for (int c = 0; c < 5; ++c) {
                ev[c]  += zv * w1b2[h*5 + c];
                t0v[c] += zv * w0b2[h*5 + c];
            }
        }
        #pragma unroll
        for (int c = 0; c < 5; ++c) {
            ev[c]  += __shfl_xor(ev[c], 1);  ev[c]  += __shfl_xor(ev[c], 2);
            t0v[c] += __shfl_xor(t0v[c], 1); t0v[c] += __shfl_xor(t0v[c], 2);
        }
        if (g == 0) {
            #pragma unroll
            for (int c = 0; c < 5; ++c) {
                eT[c*HS + row]  = f2bf(ev[c]);
                t0f[row*8 + c]  = t0v[c];
            }
        }
    }
    __syncthreads();

    // ---------- phase 7: tilde = t0 + HW@E ; x += tilde^T ----------
    {
        floatx4 acc = {0.f, 0.f, 0.f, 0.f};
        const int nse = lr < 5 ? lr : 4;
        #pragma unroll
        for (int kt = 0; kt < 4; ++kt) {
            short8 bb = *(const short8*)&eT[nse*HS + kt*32 + quad*8];
            acc = __builtin_amdgcn_mfma_f32_16x16x32_bf16(A[kt], bb, acc, 0, 0, 0);
        }
        if (lr < 5) {
            #pragma unroll
            for (int r = 0; r < 4; ++r) {
                int mm = wv*16 + quad*4 + r;
                xb[lr*KK + mm] += acc[r] + t0f[mm*8 + lr];
            }
        }
    }
    __syncthreads();

    // ---------- phase 8: f = sum(x[:K]) - PMAX (redundant per-thread) ----------
    float pv = (t < KK) ? xb[t] : 0.0f;
    #pragma unroll
    for (int s = 1; s < 64; s <<= 1) pv += __shfl_xor(pv, s);
    if (lane == 0) red[wv] = pv;
    __syncthreads();
    float fv = -PMAXV;
    #pragma unroll
    for (int w2 = 0; w2 < 8; ++w2) fv += red[w2];

    const int num_itr = num_itr_p[0], kth = kth_p[0];
    const bool flag = (kth == num_itr - 1);
    const float nu3 = nu3_p[0], tg = tg_p[0];
    const float onu = 1.0f + nu3, otg = 1.0f + tg;
    const float Vnu = 1.0f - 1.0f/(onu*onu), Vg = 1.0f - 1.0f/(otg*otg);
    float* outx = out + (size_t)b * MM;

    // ---------- phase 9: clamp + store ----------
    #pragma unroll
    for (int r2 = 0; r2 < 2; ++r2) {
        int idx = r2*512 + t;
        if (idx < MM) {
            float v = xb[idx];
            if (idx < KK && fv > 0.0f) v -= fv * (1.0f/KK);
            v = fmaxf(v, (idx >= KK   && idx < 2*KK) ? nu3 : 0.0f);
            v = fminf(v, (idx >= 2*KK && idx < 3*KK) ? tg  : BIGV);
            v = fmaxf(v, (idx >= 3*KK && idx < 4*KK) ? Vnu : 0.0f);
            v = fminf(v, (idx >= 3*KK && idx < 4*KK) ? Vg  : BIGV);
            if (flag) v = fmaxf(v, 0.0f);
            xb[idx] = v;
            outx[idx] = v;
        }
    }

    // ---------- phase 10: extra outputs (last iteration) ----------
    if (flag) {
        __syncthreads();
        const size_t O1 = (size_t)B_N*MM;
        const size_t OK = (size_t)B_N*KK;
        if (t < KK) {
            float xg = xb[2*KK + t], xv = xb[3*KK + t];
            float u1 = 1.0f + xg;
            out[O1 + (size_t)b*KK + t]      = 1.0f - 1.0f/(u1*u1) - xv;   // f5
            out[O1 + OK + (size_t)b*KK + t] = sqrtf(xv) - xb[4*KK + t];   // f6
        }
        float dp = 0.0f;    // sum_i p[i]*hw[i][col=row]
        for (int w = 0; w < 32; ++w) {
            int i = 4*w + g;
            dp += xb[i] * bf2f(hwb[i*HS + row]);
        }
        dp += __shfl_xor(dp, 1); dp += __shfl_xor(dp, 2);
        if (g == 0) {
            float p_  = xb[row], nuv = xb[KK + row], xg = xb[2*KK + row];
            float diag = bf2f(hwb[row*HS + row]);
            float top  = p_ * diag;
            float down = dp - top + 1.0f;
            out[O1 + 2*OK + (size_t)b*KK + row] = top - down * xg;        // f4
            out[O1 + 3*OK + (size_t)b*KK + row] = nuv * down - top;       // f2
        }
    }
}

extern "C" void kernel_launch(void* const* d_in, const int* in_sizes, int n_in,
                              void* d_out, int out_size, void* d_ws, size_t ws_size,
                              hipStream_t stream) {
    unfold_pocs_kernel<<<dim3(B_N), dim3(512), 0, stream>>>(
        (const int*)d_in[0], (const int*)d_in[1],
        (const float*)d_in[2], (const float*)d_in[3],
        (const float*)d_in[4], (const float*)d_in[5],
        (const float*)d_in[12], (const float*)d_in[13],
        (const float*)d_in[14], (const float*)d_in[15],
        (const float*)d_in[16], (const float*)d_in[17],
        (const float*)d_in[18], (const float*)d_in[19],
        (float*)d_out);
}